// Round 3
// baseline (649.671 us; speedup 1.0000x reference)
//
#include <hip/hip_runtime.h>

#define V 32000
#define H 256
#define S 2048
#define B 128
#define NC 64   // score/ctx chunks per b
#define CS 32   // s-rows per chunk

// K1: u[b,t] = sum_k h[b,k] * We[k,t],  We[k,t] = attn_W[k*2H + H + t]
__global__ __launch_bounds__(256) void k_u(const float* __restrict__ hid,
                                           const float* __restrict__ attn_W,
                                           float* __restrict__ u) {
    __shared__ float hl[H];
    int b = blockIdx.x, t = threadIdx.x;
    hl[t] = hid[b * H + t];
    __syncthreads();
    float acc = 0.f;
    for (int k = 0; k < H; ++k)
        acc += hl[k] * attn_W[k * (2 * H) + H + t];
    u[b * H + t] = acc;
}

// K2: per (b, chunk): scores, chunk-softmax stats, partial context. enc read ONCE.
__global__ __launch_bounds__(256) void k_scores(const float* __restrict__ enc,
                                                const float* __restrict__ u,
                                                float* __restrict__ scores,
                                                float* __restrict__ part_m,
                                                float* __restrict__ part_l,
                                                float* __restrict__ ctx_part) {
    __shared__ float encl[CS * H];
    __shared__ float ul[H];
    __shared__ float sl[CS];
    __shared__ float wx[CS];
    int b = blockIdx.x, c = blockIdx.y, t = threadIdx.x;
    ul[t] = u[b * H + t];
    int s0 = c * CS;
    // stage enc tile, coalesced float4 loads
    for (int i = t; i < CS * (H / 4); i += 256) {
        int row = i >> 6;          // H/4 = 64 vec4 per row
        int col = (i & 63) << 2;
        float4 f = *(const float4*)(enc + ((size_t)(s0 + row) * B + b) * H + col);
        *(float4*)(encl + row * H + col) = f;
    }
    __syncthreads();
    int w = t >> 6, l = t & 63;
    // each wave: 8 score rows
    for (int j = 0; j < 8; ++j) {
        int s = w * 8 + j;
        float4 e = *(const float4*)(encl + s * H + l * 4);
        float4 uu = *(const float4*)(ul + l * 4);
        float v = e.x * uu.x + e.y * uu.y + e.z * uu.z + e.w * uu.w;
        for (int off = 32; off; off >>= 1) v += __shfl_xor(v, off, 64);
        if (l == 0) {
            sl[s] = v;
            scores[(size_t)b * S + s0 + s] = v;
        }
    }
    __syncthreads();
    if (t < CS) {
        float m = sl[t];
        for (int off = 16; off; off >>= 1) m = fmaxf(m, __shfl_xor(m, off, 64));
        m = __shfl(m, 0, 64);  // broadcast (partners stay in lanes 0..31)
        float e = __expf(sl[t] - m);
        wx[t] = e;
        float lsum = e;
        for (int off = 16; off; off >>= 1) lsum += __shfl_xor(lsum, off, 64);
        if (t == 0) {
            int pc = b * NC + c;
            part_m[pc] = m;
            part_l[pc] = lsum;
        }
    }
    __syncthreads();
    float acc = 0.f;
    for (int s = 0; s < CS; ++s) acc += wx[s] * encl[s * H + t];
    ctx_part[((size_t)(b * NC + c)) * H + t] = acc;
}

// K3: combine chunk partials -> context (into x2 upper half) + attn_weights out
__global__ __launch_bounds__(256) void k_combine(const float* __restrict__ part_m,
                                                 const float* __restrict__ part_l,
                                                 const float* __restrict__ ctx_part,
                                                 const float* __restrict__ scores,
                                                 float* __restrict__ x2,
                                                 float* __restrict__ out_attn) {
    __shared__ float wf[NC];
    __shared__ float Ms, Ls;
    int b = blockIdx.x, t = threadIdx.x;
    if (t < NC) {
        float m = part_m[b * NC + t];
        float M = m;
        for (int off = 32; off; off >>= 1) M = fmaxf(M, __shfl_xor(M, off, 64));
        M = __shfl(M, 0, 64);
        float e = __expf(m - M);
        wf[t] = e;
        float lw = e * part_l[b * NC + t];
        for (int off = 32; off; off >>= 1) lw += __shfl_xor(lw, off, 64);
        if (t == 0) { Ms = M; Ls = lw; }
    }
    __syncthreads();
    float M = Ms, invL = 1.0f / Ls;
    float acc = 0.f;
    for (int c = 0; c < NC; ++c)
        acc += wf[c] * ctx_part[((size_t)(b * NC + c)) * H + t];
    x2[b * (2 * H) + H + t] = acc * invL;   // context (normalized!)
    for (int s = t; s < S; s += 256) {
        out_attn[(size_t)b * S + s] = __expf(scores[(size_t)b * S + s] - M) * invL;
    }
}

// K4: GRU cell. Block = one b, 768 threads = 12 waves.
// Each wave row-reduces 64 rows of W_ih and W_hh with lane-coalesced float4 loads.
__global__ __launch_bounds__(768) void k_gru(const int* __restrict__ ids,
                                             const float* __restrict__ hid,
                                             const float* __restrict__ emb,
                                             const float* __restrict__ W_ih,
                                             const float* __restrict__ W_hh,
                                             const float* __restrict__ b_ih,
                                             const float* __restrict__ b_hh,
                                             float* __restrict__ x2,
                                             float* __restrict__ out_h) {
    __shared__ float xl[2 * H];
    __shared__ float hl[H];
    __shared__ float gis[3 * H];
    __shared__ float ghs[3 * H];
    int b = blockIdx.x, t = threadIdx.x;
    if (t < H) xl[t] = emb[(size_t)ids[b] * H + t];
    else if (t < 2 * H) xl[t] = x2[b * (2 * H) + t];   // context half
    else hl[t - 2 * H] = hid[b * H + (t - 2 * H)];
    __syncthreads();
    int w = t >> 6, l = t & 63;
    float4 xa = *(const float4*)(xl + 4 * l);
    float4 xb = *(const float4*)(xl + H + 4 * l);
    float4 ha = *(const float4*)(hl + 4 * l);
    for (int jj = 0; jj < 64; ++jj) {
        int j = w * 64 + jj;
        const float* wr = W_ih + (size_t)j * (2 * H);
        float4 w1 = *(const float4*)(wr + 4 * l);
        float4 w2 = *(const float4*)(wr + H + 4 * l);
        float vi = w1.x * xa.x + w1.y * xa.y + w1.z * xa.z + w1.w * xa.w
                 + w2.x * xb.x + w2.y * xb.y + w2.z * xb.z + w2.w * xb.w;
        const float* vr = W_hh + (size_t)j * H;
        float4 w3 = *(const float4*)(vr + 4 * l);
        float vh = w3.x * ha.x + w3.y * ha.y + w3.z * ha.z + w3.w * ha.w;
        for (int off = 32; off; off >>= 1) {
            vi += __shfl_xor(vi, off, 64);
            vh += __shfl_xor(vh, off, 64);
        }
        if (l == 0) {
            gis[j] = vi + b_ih[j];
            ghs[j] = vh + b_hh[j];
        }
    }
    __syncthreads();
    if (t < H) {
        float r = 1.f / (1.f + __expf(-(gis[t] + ghs[t])));
        float z = 1.f / (1.f + __expf(-(gis[H + t] + ghs[H + t])));
        float n = tanhf(gis[2 * H + t] + r * ghs[2 * H + t]);
        float hn = (1.f - z) * n + z * hl[t];
        out_h[b * H + t] = hn;
        x2[b * (2 * H) + t] = hn;
    }
}

// K5: logits[b, v] = x2[b,:] . out_W[:, v] + out_b[v]
// thread: 4 v's; block: 1024 v x 8 b; grid (32 v-tiles, 16 b-tiles)
// NOTE: 32*1024 = 32768 > V=32000 -> tail guard is REQUIRED (R2 bug: dropped
// guard let block x=31 scribble into the next batch row => absmax 5.25).
#define BT 8
__global__ __launch_bounds__(256) void k_logits(const float* __restrict__ x2,
                                                const float* __restrict__ out_W,
                                                const float* __restrict__ out_b,
                                                float* __restrict__ logits) {
    int t = threadIdx.x;
    int v0 = blockIdx.x * 1024 + 4 * t;
    int b0 = blockIdx.y * BT;
    if (v0 >= V) return;
    float4 ob = *(const float4*)(out_b + v0);
    float acc[BT][4];
    for (int bb = 0; bb < BT; ++bb) {
        acc[bb][0] = ob.x; acc[bb][1] = ob.y; acc[bb][2] = ob.z; acc[bb][3] = ob.w;
    }
    for (int k = 0; k < 2 * H; k += 4) {
        float w[4][4];
        for (int ku = 0; ku < 4; ++ku) {
            float4 wv = *(const float4*)(out_W + (size_t)(k + ku) * V + v0);
            w[ku][0] = wv.x; w[ku][1] = wv.y; w[ku][2] = wv.z; w[ku][3] = wv.w;
        }
        for (int bb = 0; bb < BT; ++bb) {
            const float* xp = x2 + ((b0 + bb) << 9) + k;   // wave-uniform -> s_load
            float x0 = xp[0], x1 = xp[1], xv2 = xp[2], x3 = xp[3];
            for (int jj = 0; jj < 4; ++jj)
                acc[bb][jj] += x0 * w[0][jj] + x1 * w[1][jj] + xv2 * w[2][jj] + x3 * w[3][jj];
        }
    }
    for (int bb = 0; bb < BT; ++bb) {
        float4 r = make_float4(acc[bb][0], acc[bb][1], acc[bb][2], acc[bb][3]);
        *(float4*)(logits + (size_t)(b0 + bb) * V + v0) = r;
    }
}

// K6a: per (chunk, b) partial max / sumexp over 4000 logits
__global__ __launch_bounds__(256) void k_lsm_part(const float* __restrict__ logits,
                                                  float* __restrict__ pm,
                                                  float* __restrict__ pl) {
    __shared__ float wm[4];
    __shared__ float wsum[4];
    int c = blockIdx.x, b = blockIdx.y, t = threadIdx.x;
    const float* row = logits + (size_t)b * V + c * 4000;
    float m = -1e30f;
    for (int i = t; i < 4000; i += 256) m = fmaxf(m, row[i]);
    for (int off = 32; off; off >>= 1) m = fmaxf(m, __shfl_xor(m, off, 64));
    if ((t & 63) == 0) wm[t >> 6] = m;
    __syncthreads();
    float M = fmaxf(fmaxf(wm[0], wm[1]), fmaxf(wm[2], wm[3]));
    float sacc = 0.f;
    for (int i = t; i < 4000; i += 256) sacc += __expf(row[i] - M);
    for (int off = 32; off; off >>= 1) sacc += __shfl_xor(sacc, off, 64);
    if ((t & 63) == 0) wsum[t >> 6] = sacc;
    __syncthreads();
    if (t == 0) {
        pm[b * 8 + c] = M;
        pl[b * 8 + c] = wsum[0] + wsum[1] + wsum[2] + wsum[3];
    }
}

// K6b: combine 8 partials per row -> M_b, log L_b
__global__ __launch_bounds__(128) void k_lsm_comb(const float* __restrict__ pm,
                                                  const float* __restrict__ pl,
                                                  float* __restrict__ Ml,
                                                  float* __restrict__ Ll) {
    int b = threadIdx.x;
    float M = -1e30f;
    for (int c = 0; c < 8; ++c) M = fmaxf(M, pm[b * 8 + c]);
    float L = 0.f;
    for (int c = 0; c < 8; ++c) L += pl[b * 8 + c] * __expf(pm[b * 8 + c] - M);
    Ml[b] = M;
    Ll[b] = logf(L);
}

// K6c: out[b,v] = logit - M_b - logL_b  (same tail guard as k_logits!)
__global__ __launch_bounds__(256) void k_lsm_write(const float* __restrict__ logits,
                                                   const float* __restrict__ Ml,
                                                   const float* __restrict__ Ll,
                                                   float* __restrict__ out) {
    int b = blockIdx.y, t = threadIdx.x;
    int v = blockIdx.x * 1024 + 4 * t;
    if (v >= V) return;
    float off = Ml[b] + Ll[b];
    float4 x = *(const float4*)(logits + (size_t)b * V + v);
    float4 o = make_float4(x.x - off, x.y - off, x.z - off, x.w - off);
    *(float4*)(out + (size_t)b * V + v) = o;
}

extern "C" void kernel_launch(void* const* d_in, const int* in_sizes, int n_in,
                              void* d_out, int out_size, void* d_ws, size_t ws_size,
                              hipStream_t stream) {
    const int* ids = (const int*)d_in[0];
    const float* hid = (const float*)d_in[1];
    const float* enc = (const float*)d_in[2];
    const float* emb = (const float*)d_in[3];
    const float* attn_W = (const float*)d_in[4];
    // d_in[5] attn_b: unused (per-row constant shift, softmax-invariant)
    const float* W_ih = (const float*)d_in[6];
    const float* W_hh = (const float*)d_in[7];
    const float* b_ih = (const float*)d_in[8];
    const float* b_hh = (const float*)d_in[9];
    const float* out_W = (const float*)d_in[10];
    const float* out_b = (const float*)d_in[11];

    float* out = (float*)d_out;
    float* out_logprob = out;                        // B*V
    float* out_h = out + (size_t)B * V;              // B*H
    float* out_attn = out + (size_t)B * V + B * H;   // B*S

    float* w = (float*)d_ws;
    float* u        = w;                    // 32768
    float* scores   = w + 32768;            // 262144
    float* part_m   = w + 294912;           // 8192
    float* part_l   = w + 303104;           // 8192
    float* ctx_part = w + 311296;           // 2097152
    float* x2       = w + 2408448;          // 65536
    float* logits   = w + 2473984;          // 4096000
    float* lsm      = w + 6569984;          // 1024
    float* lsl      = w + 6571008;          // 1024
    float* Ml       = w + 6572032;          // 128
    float* Ll       = w + 6572160;          // 128

    hipLaunchKernelGGL(k_u, dim3(B), dim3(256), 0, stream, hid, attn_W, u);
    hipLaunchKernelGGL(k_scores, dim3(B, NC), dim3(256), 0, stream,
                       enc, u, scores, part_m, part_l, ctx_part);
    hipLaunchKernelGGL(k_combine, dim3(B), dim3(256), 0, stream,
                       part_m, part_l, ctx_part, scores, x2, out_attn);
    hipLaunchKernelGGL(k_gru, dim3(B), dim3(768), 0, stream,
                       ids, hid, emb, W_ih, W_hh, b_ih, b_hh, x2, out_h);
    hipLaunchKernelGGL(k_logits, dim3(32, 16), dim3(256), 0, stream,
                       x2, out_W, out_b, logits);
    hipLaunchKernelGGL(k_lsm_part, dim3(8, B), dim3(256), 0, stream, logits, lsm, lsl);
    hipLaunchKernelGGL(k_lsm_comb, dim3(1), dim3(128), 0, stream, lsm, lsl, Ml, Ll);
    hipLaunchKernelGGL(k_lsm_write, dim3(32, B), dim3(256), 0, stream,
                       logits, Ml, Ll, out_logprob);
}